// Round 3
// baseline (363.159 us; speedup 1.0000x reference)
//
#include <hip/hip_runtime.h>
#include <hip/hip_bf16.h>

// SelfAttention2D: B=4, C=256, H=W=64, N=4096, Cqk=32.
// Round 3: barrier-free register-resident flash attention.
//  - K stored row-PERMUTED (sigma: 16kt+4quad+r -> 8quad+4kt+r) so the S^T
//    MFMA's C-layout IS the P B-frag layout in-register: no LDS, no barriers.
//  - PV as mfma(V as A, P as B) -> O transposed -> coalesced fp32 stores.
//  - 8 waves/block = 4 row-tiles x 2 ch-halves; V frags shared via L1;
//    depth-1 register prefetch; raw s_barrier every 64 keys for wave
//    alignment (no waitcnt drain - no shared memory semantics needed).

typedef __attribute__((ext_vector_type(8))) short s8v;  // 8 bf16 (MFMA A/B frag)
typedef __attribute__((ext_vector_type(4))) float f4v;  // MFMA C/D frag

#define NPIX 4096
#define CIN 256
#define DQK 32

#if __has_builtin(__builtin_amdgcn_exp2f)
#define EXP2(x) __builtin_amdgcn_exp2f(x)
#else
#define EXP2(x) exp2f(x)
#endif

static __device__ __forceinline__ unsigned short f2bf(float f) {
    union { float f; unsigned int u; } v; v.f = f;
    unsigned int r = v.u + 0x7FFF + ((v.u >> 16) & 1);   // RTNE
    return (unsigned short)(r >> 16);
}
static __device__ __forceinline__ unsigned int fbits(float f) {
    union { float f; unsigned int u; } v; v.f = f; return v.u;
}

// ---------------------------------------------------------------------------
// Kernel 1: pack Wq/Wk/Wv -> bf16 Wall[320][256], biases -> fp32 ball[320].
__global__ void wcast_kernel(const float* __restrict__ Wq, const float* __restrict__ bq,
                             const float* __restrict__ Wk, const float* __restrict__ bk,
                             const float* __restrict__ Wv, const float* __restrict__ bv,
                             unsigned short* __restrict__ Wall, float* __restrict__ ball) {
    int row = blockIdx.x;
    int t = threadIdx.x;
    const float* src; const float* bsrc;
    if (row < 32)       { src = Wq + row * 256;        bsrc = bq + row; }
    else if (row < 64)  { src = Wk + (row - 32) * 256; bsrc = bk + (row - 32); }
    else                { src = Wv + (row - 64) * 256; bsrc = bv + (row - 64); }
    Wall[row * 256 + t] = f2bf(src[t]);
    if (t == 0) ball[row] = bsrc[0];
}

// ---------------------------------------------------------------------------
// Kernel 2: x[b][c][n] fp32 -> xT[b][n][c] bf16 (64x64 LDS tile transpose).
__global__ void tcast_kernel(const float* __restrict__ x, unsigned short* __restrict__ xT) {
    __shared__ unsigned short tile[64][65];
    int bidx = blockIdx.x;
    int b    = bidx >> 8;
    int cblk = (bidx >> 6) & 3;
    int nblk = bidx & 63;
    int t = threadIdx.x;
    int c0 = cblk * 64, n0 = nblk * 64;
    const float* xb = x + (size_t)b * CIN * NPIX;
    #pragma unroll
    for (int p = 0; p < 4; p++) {
        int cl = p * 16 + (t >> 4);
        int nl = (t & 15) * 4;
        float4 v = *(const float4*)(xb + (size_t)(c0 + cl) * NPIX + n0 + nl);
        tile[cl][nl + 0] = f2bf(v.x);
        tile[cl][nl + 1] = f2bf(v.y);
        tile[cl][nl + 2] = f2bf(v.z);
        tile[cl][nl + 3] = f2bf(v.w);
    }
    __syncthreads();
    unsigned short* xTb = xT + (size_t)b * NPIX * CIN;
    #pragma unroll
    for (int p = 0; p < 4; p++) {
        int nl = p * 16 + (t >> 4);
        int cl = (t & 15) * 4;
        ushort4 wv;
        wv.x = tile[cl + 0][nl];
        wv.y = tile[cl + 1][nl];
        wv.z = tile[cl + 2][nl];
        wv.w = tile[cl + 3][nl];
        *(ushort4*)(xTb + (size_t)(n0 + nl) * CIN + c0 + cl) = wv;
    }
}

// ---------------------------------------------------------------------------
// Kernel 3: projection GEMM. grid = 256 blocks (XCD-swizzled b,nblk decode),
// 4 waves x 16 n-rows each. Each wave holds its xT frags (dual-role A/B) and
// sweeps all 20 oc-blocks in pairs (2 indep MFMA chains).
//  Q  (ob 0,1): mfma(xT, W) -> lane=oc -> coalesced [n][32] stores, *log2(e)
//  K~ (ob 2,3): same, but row target sigma^-1(n) (permuted within 32-groups)
//  V  (ob 4..19): mfma(W, xT) -> lane=n -> coalesced Vt[ch][n] stores
__global__ __launch_bounds__(256)
void proj_kernel(const unsigned short* __restrict__ xT,
                 const unsigned short* __restrict__ Wall,
                 const float* __restrict__ ball,
                 unsigned short* __restrict__ Q,
                 unsigned short* __restrict__ Kp,
                 unsigned short* __restrict__ Vt) {
    int idx  = blockIdx.x;
    int b    = (idx & 7) >> 1;                       // match attn's XCD affinity
    int nblk = ((idx >> 3) << 1) | (idx & 1);
    int w    = threadIdx.x >> 6;
    int lane = threadIdx.x & 63;
    int l16 = lane & 15, quad = lane >> 4;
    int n0 = nblk * 64 + w * 16;

    const unsigned short* brow = xT + (size_t)(b * NPIX + n0 + l16) * CIN + quad * 8;
    s8v bfr[8];
    #pragma unroll
    for (int kk = 0; kk < 8; kk++) bfr[kk] = *(const s8v*)(brow + kk * 32);

    #pragma unroll
    for (int p = 0; p < 10; p++) {
        const unsigned short* w0 = Wall + (size_t)(2 * p * 16 + l16) * CIN + quad * 8;
        const unsigned short* w1 = w0 + 16 * CIN;
        f4v a0 = {0.f, 0.f, 0.f, 0.f}, a1 = {0.f, 0.f, 0.f, 0.f};
        if (p < 2) {  // Q/K: A=xT(rows=n), B=W(cols=oc)
            #pragma unroll
            for (int kk = 0; kk < 8; kk++) {
                a0 = __builtin_amdgcn_mfma_f32_16x16x32_bf16(bfr[kk], *(const s8v*)(w0 + kk * 32), a0, 0, 0, 0);
                a1 = __builtin_amdgcn_mfma_f32_16x16x32_bf16(bfr[kk], *(const s8v*)(w1 + kk * 32), a1, 0, 0, 0);
            }
        } else {      // V: A=W(rows=ch), B=xT(cols=n)
            #pragma unroll
            for (int kk = 0; kk < 8; kk++) {
                a0 = __builtin_amdgcn_mfma_f32_16x16x32_bf16(*(const s8v*)(w0 + kk * 32), bfr[kk], a0, 0, 0, 0);
                a1 = __builtin_amdgcn_mfma_f32_16x16x32_bf16(*(const s8v*)(w1 + kk * 32), bfr[kk], a1, 0, 0, 0);
            }
        }
        #pragma unroll
        for (int half = 0; half < 2; half++) {
            int ob = 2 * p + half;
            f4v acc = half ? a1 : a0;
            if (ob < 2) {            // Q: lane l16 = oc, reg r -> n-sub
                int oc = ob * 16 + l16;
                float bias = ball[oc];
                #pragma unroll
                for (int r = 0; r < 4; r++) {
                    int n = n0 + quad * 4 + r;
                    Q[(size_t)(b * NPIX + n) * DQK + oc] =
                        f2bf((acc[r] + bias) * 1.44269504f);
                }
            } else if (ob < 4) {     // K~: permuted row sigma^-1(n)
                int oc = (ob - 2) * 16 + l16;
                float bias = ball[32 + oc];
                #pragma unroll
                for (int r = 0; r < 4; r++) {
                    int n = n0 + quad * 4 + r;
                    int pn = (n & ~31) | (((n >> 2) & 1) << 4) | (((n >> 3) & 3) << 2) | (n & 3);
                    Kp[(size_t)(b * NPIX + pn) * DQK + oc] = f2bf(acc[r] + bias);
                }
            } else {                 // V: lane l16 = n, reg r -> ch-sub
                int n = n0 + l16;
                #pragma unroll
                for (int r = 0; r < 4; r++) {
                    int ch = (ob - 4) * 16 + quad * 4 + r;
                    Vt[((size_t)b * CIN + ch) * NPIX + n] = f2bf(acc[r] + ball[64 + ch]);
                }
            }
        }
    }
}

// ---------------------------------------------------------------------------
// Kernel 4: flash attention, no LDS, no __syncthreads.
// 8 waves: w = rt*2 + cg; wave owns rows [rowblk*64 + rt*16, +16) x
// ch [cg*128, +128) over all 4096 keys (32/iter). S duplicated x2 (cg pair).
#define ATTN_STEP(KC0, KC1, VC, KN0, KN1, VN, NKV)                              \
    {                                                                           \
        KN0 = *(const s8v*)(kbase + (size_t)(NKV) * DQK);                       \
        KN1 = *(const s8v*)(kbase + (size_t)((NKV) + 16) * DQK);                \
        _Pragma("unroll")                                                       \
        for (int ct = 0; ct < 8; ct++)                                          \
            VN[ct] = *(const s8v*)(vbase + (size_t)ct * 16 * NPIX + (NKV));     \
        f4v s0 = {0.f, 0.f, 0.f, 0.f}, s1 = {0.f, 0.f, 0.f, 0.f};               \
        s0 = __builtin_amdgcn_mfma_f32_16x16x32_bf16(KC0, qfrag, s0, 0, 0, 0);  \
        s1 = __builtin_amdgcn_mfma_f32_16x16x32_bf16(KC1, qfrag, s1, 0, 0, 0);  \
        float p00 = EXP2(s0[0]), p01 = EXP2(s0[1]);                             \
        float p02 = EXP2(s0[2]), p03 = EXP2(s0[3]);                             \
        float p10 = EXP2(s1[0]), p11 = EXP2(s1[1]);                             \
        float p12 = EXP2(s1[2]), p13 = EXP2(s1[3]);                             \
        lsum += ((p00 + p01) + (p02 + p03)) + ((p10 + p11) + (p12 + p13));      \
        union { uint4 u; s8v v; } pu;                                           \
        pu.u.x = __builtin_amdgcn_perm(fbits(p01), fbits(p00), 0x07060302);     \
        pu.u.y = __builtin_amdgcn_perm(fbits(p03), fbits(p02), 0x07060302);     \
        pu.u.z = __builtin_amdgcn_perm(fbits(p11), fbits(p10), 0x07060302);     \
        pu.u.w = __builtin_amdgcn_perm(fbits(p13), fbits(p12), 0x07060302);     \
        _Pragma("unroll")                                                       \
        for (int ct = 0; ct < 8; ct++)                                          \
            O[ct] = __builtin_amdgcn_mfma_f32_16x16x32_bf16(VC[ct], pu.v, O[ct], 0, 0, 0); \
    }

__global__ __launch_bounds__(512)
void attn_kernel(const unsigned short* __restrict__ Q,
                 const unsigned short* __restrict__ Kp,
                 const unsigned short* __restrict__ Vt,
                 const float* __restrict__ gamma,
                 float* __restrict__ out) {
    int idx = blockIdx.x;
    int b      = (idx & 7) >> 1;                    // batch -> XCD pair {2b,2b+1}
    int rowblk = ((idx >> 3) << 1) | (idx & 1);

    int lane = threadIdx.x & 63;
    int w    = threadIdx.x >> 6;
    int l16 = lane & 15, quad = lane >> 4;
    int rt = w >> 1;   // row-tile 0..3
    int cg = w & 1;    // ch-half 0..1

    const unsigned short* Kb = Kp + (size_t)b * NPIX * DQK;
    const unsigned short* Vb = Vt + (size_t)b * CIN * NPIX;

    // Q B-frag (rows of rt), log2(e) pre-folded
    const s8v qfrag = *(const s8v*)(Q + (size_t)(b * NPIX + rowblk * 64 + rt * 16 + l16) * DQK + quad * 8);

    const unsigned short* kbase = Kb + (size_t)l16 * DQK + quad * 8;
    const unsigned short* vbase = Vb + (size_t)(cg * 128 + l16) * NPIX + quad * 8;

    f4v O[8];
    #pragma unroll
    for (int ct = 0; ct < 8; ct++) O[ct] = (f4v){0.f, 0.f, 0.f, 0.f};
    float lsum = 0.f;

    s8v Vc[8], Vn[8], Kc0, Kc1, Kn0, Kn1;
    Kc0 = *(const s8v*)(kbase);
    Kc1 = *(const s8v*)(kbase + 16 * DQK);
    #pragma unroll
    for (int ct = 0; ct < 8; ct++)
        Vc[ct] = *(const s8v*)(vbase + (size_t)ct * 16 * NPIX);

    for (int kv2 = 0; kv2 < NPIX; kv2 += 64) {
        ATTN_STEP(Kc0, Kc1, Vc, Kn0, Kn1, Vn, kv2 + 32);
        ATTN_STEP(Kn0, Kn1, Vn, Kc0, Kc1, Vc, (kv2 + 64) & (NPIX - 1));
        __builtin_amdgcn_s_barrier();   // raw barrier: loose wave alignment for
                                        // L1 V-frag sharing; no waitcnt drain
    }

    // full row-sum for row rt*16+l16 (reduce over quads)
    lsum += __shfl_xor(lsum, 16);
    lsum += __shfl_xor(lsum, 32);
    float rinv = gamma[0] / lsum;

    int row = rowblk * 64 + rt * 16 + l16;
    #pragma unroll
    for (int ct = 0; ct < 8; ct++) {
        #pragma unroll
        for (int r = 0; r < 4; r++) {
            int ch = cg * 128 + ct * 16 + quad * 4 + r;
            out[((size_t)b * CIN + ch) * NPIX + row] = O[ct][r] * rinv;
        }
    }
}

// ---------------------------------------------------------------------------
extern "C" void kernel_launch(void* const* d_in, const int* in_sizes, int n_in,
                              void* d_out, int out_size, void* d_ws, size_t ws_size,
                              hipStream_t stream) {
    const float* x     = (const float*)d_in[0];
    const float* Wq    = (const float*)d_in[1];
    const float* bq    = (const float*)d_in[2];
    const float* Wk    = (const float*)d_in[3];
    const float* bk    = (const float*)d_in[4];
    const float* Wv    = (const float*)d_in[5];
    const float* bv    = (const float*)d_in[6];
    const float* gamma = (const float*)d_in[7];
    float* out = (float*)d_out;

    char* p = (char*)d_ws;
    unsigned short* xT   = (unsigned short*)p; p += (size_t)4 * NPIX * CIN * 2;   // 8 MB
    unsigned short* Qb   = (unsigned short*)p; p += (size_t)4 * NPIX * DQK * 2;   // 1 MB
    unsigned short* Kb   = (unsigned short*)p; p += (size_t)4 * NPIX * DQK * 2;   // 1 MB
    unsigned short* Vt   = (unsigned short*)p; p += (size_t)4 * CIN * NPIX * 2;   // 8 MB
    unsigned short* Wall = (unsigned short*)p; p += (size_t)320 * 256 * 2;
    float*          ball = (float*)p;          p += (size_t)320 * 4;

    wcast_kernel<<<320, 256, 0, stream>>>(Wq, bq, Wk, bk, Wv, bv, Wall, ball);
    tcast_kernel<<<1024, 256, 0, stream>>>(x, xT);
    proj_kernel<<<256, 256, 0, stream>>>(xT, Wall, ball, Qb, Kb, Vt);
    attn_kernel<<<256, 512, 0, stream>>>(Qb, Kb, Vt, gamma, out);
}

// Round 4
// 185.065 us; speedup vs baseline: 1.9623x; 1.9623x over previous
//
#include <hip/hip_runtime.h>
#include <hip/hip_bf16.h>

// SelfAttention2D: B=4, C=256, H=W=64, N=4096, Cqk=32.
// Round 4: load-deduplicated register-resident flash attention.
//  - Wave partition = (key-half kh x 64-ch slice cs): each wave computes
//    S/P for ALL 64 q-rows (register P via K-permutation trick) but loads
//    only its own ch-slice of V and half the keys -> issued bytes per CU
//    per key drop 2.5KB -> 0.75KB (V exactly once, K 4x).
//  - O (64 rows x 64 ch per wave) in 64 accs; kh-halves combined once at
//    the end via LDS (linear combine exact: no running max).
//  - No per-iter barriers; depth-1 prefetch; one __syncthreads total.

typedef __attribute__((ext_vector_type(8))) short s8v;  // 8 bf16 (MFMA A/B frag)
typedef __attribute__((ext_vector_type(4))) float f4v;  // MFMA C/D frag

#define NPIX 4096
#define CIN 256
#define DQK 32

#if __has_builtin(__builtin_amdgcn_exp2f)
#define EXP2(x) __builtin_amdgcn_exp2f(x)
#else
#define EXP2(x) exp2f(x)
#endif

static __device__ __forceinline__ unsigned short f2bf(float f) {
    union { float f; unsigned int u; } v; v.f = f;
    unsigned int r = v.u + 0x7FFF + ((v.u >> 16) & 1);   // RTNE
    return (unsigned short)(r >> 16);
}
static __device__ __forceinline__ unsigned int fbits(float f) {
    union { float f; unsigned int u; } v; v.f = f; return v.u;
}

// ---------------------------------------------------------------------------
// Kernel 1: pack Wq/Wk/Wv -> bf16 Wall[320][256], biases -> fp32 ball[320].
__global__ void wcast_kernel(const float* __restrict__ Wq, const float* __restrict__ bq,
                             const float* __restrict__ Wk, const float* __restrict__ bk,
                             const float* __restrict__ Wv, const float* __restrict__ bv,
                             unsigned short* __restrict__ Wall, float* __restrict__ ball) {
    int row = blockIdx.x;
    int t = threadIdx.x;
    const float* src; const float* bsrc;
    if (row < 32)       { src = Wq + row * 256;        bsrc = bq + row; }
    else if (row < 64)  { src = Wk + (row - 32) * 256; bsrc = bk + (row - 32); }
    else                { src = Wv + (row - 64) * 256; bsrc = bv + (row - 64); }
    Wall[row * 256 + t] = f2bf(src[t]);
    if (t == 0) ball[row] = bsrc[0];
}

// ---------------------------------------------------------------------------
// Kernel 2: x[b][c][n] fp32 -> xT[b][n][c] bf16 (64x64 LDS tile transpose).
__global__ void tcast_kernel(const float* __restrict__ x, unsigned short* __restrict__ xT) {
    __shared__ unsigned short tile[64][65];
    int bidx = blockIdx.x;
    int b    = bidx >> 8;
    int cblk = (bidx >> 6) & 3;
    int nblk = bidx & 63;
    int t = threadIdx.x;
    int c0 = cblk * 64, n0 = nblk * 64;
    const float* xb = x + (size_t)b * CIN * NPIX;
    #pragma unroll
    for (int p = 0; p < 4; p++) {
        int cl = p * 16 + (t >> 4);
        int nl = (t & 15) * 4;
        float4 v = *(const float4*)(xb + (size_t)(c0 + cl) * NPIX + n0 + nl);
        tile[cl][nl + 0] = f2bf(v.x);
        tile[cl][nl + 1] = f2bf(v.y);
        tile[cl][nl + 2] = f2bf(v.z);
        tile[cl][nl + 3] = f2bf(v.w);
    }
    __syncthreads();
    unsigned short* xTb = xT + (size_t)b * NPIX * CIN;
    #pragma unroll
    for (int p = 0; p < 4; p++) {
        int nl = p * 16 + (t >> 4);
        int cl = (t & 15) * 4;
        ushort4 wv;
        wv.x = tile[cl + 0][nl];
        wv.y = tile[cl + 1][nl];
        wv.z = tile[cl + 2][nl];
        wv.w = tile[cl + 3][nl];
        *(ushort4*)(xTb + (size_t)(n0 + nl) * CIN + c0 + cl) = wv;
    }
}

// ---------------------------------------------------------------------------
// Kernel 3: projection GEMM (unchanged from round 3 - verified).
__global__ __launch_bounds__(256)
void proj_kernel(const unsigned short* __restrict__ xT,
                 const unsigned short* __restrict__ Wall,
                 const float* __restrict__ ball,
                 unsigned short* __restrict__ Q,
                 unsigned short* __restrict__ Kp,
                 unsigned short* __restrict__ Vt) {
    int idx  = blockIdx.x;
    int b    = (idx & 7) >> 1;
    int nblk = ((idx >> 3) << 1) | (idx & 1);
    int w    = threadIdx.x >> 6;
    int lane = threadIdx.x & 63;
    int l16 = lane & 15, quad = lane >> 4;
    int n0 = nblk * 64 + w * 16;

    const unsigned short* brow = xT + (size_t)(b * NPIX + n0 + l16) * CIN + quad * 8;
    s8v bfr[8];
    #pragma unroll
    for (int kk = 0; kk < 8; kk++) bfr[kk] = *(const s8v*)(brow + kk * 32);

    #pragma unroll
    for (int p = 0; p < 10; p++) {
        const unsigned short* w0 = Wall + (size_t)(2 * p * 16 + l16) * CIN + quad * 8;
        const unsigned short* w1 = w0 + 16 * CIN;
        f4v a0 = {0.f, 0.f, 0.f, 0.f}, a1 = {0.f, 0.f, 0.f, 0.f};
        if (p < 2) {  // Q/K: A=xT(rows=n), B=W(cols=oc)
            #pragma unroll
            for (int kk = 0; kk < 8; kk++) {
                a0 = __builtin_amdgcn_mfma_f32_16x16x32_bf16(bfr[kk], *(const s8v*)(w0 + kk * 32), a0, 0, 0, 0);
                a1 = __builtin_amdgcn_mfma_f32_16x16x32_bf16(bfr[kk], *(const s8v*)(w1 + kk * 32), a1, 0, 0, 0);
            }
        } else {      // V: A=W(rows=ch), B=xT(cols=n)
            #pragma unroll
            for (int kk = 0; kk < 8; kk++) {
                a0 = __builtin_amdgcn_mfma_f32_16x16x32_bf16(*(const s8v*)(w0 + kk * 32), bfr[kk], a0, 0, 0, 0);
                a1 = __builtin_amdgcn_mfma_f32_16x16x32_bf16(*(const s8v*)(w1 + kk * 32), bfr[kk], a1, 0, 0, 0);
            }
        }
        #pragma unroll
        for (int half = 0; half < 2; half++) {
            int ob = 2 * p + half;
            f4v acc = half ? a1 : a0;
            if (ob < 2) {            // Q: lane l16 = oc, reg r -> n-sub
                int oc = ob * 16 + l16;
                float bias = ball[oc];
                #pragma unroll
                for (int r = 0; r < 4; r++) {
                    int n = n0 + quad * 4 + r;
                    Q[(size_t)(b * NPIX + n) * DQK + oc] =
                        f2bf((acc[r] + bias) * 1.44269504f);
                }
            } else if (ob < 4) {     // K~: permuted row sigma^-1(n)
                int oc = (ob - 2) * 16 + l16;
                float bias = ball[32 + oc];
                #pragma unroll
                for (int r = 0; r < 4; r++) {
                    int n = n0 + quad * 4 + r;
                    int pn = (n & ~31) | (((n >> 2) & 1) << 4) | (((n >> 3) & 3) << 2) | (n & 3);
                    Kp[(size_t)(b * NPIX + pn) * DQK + oc] = f2bf(acc[r] + bias);
                }
            } else {                 // V: lane l16 = n, reg r -> ch-sub
                int n = n0 + l16;
                #pragma unroll
                for (int r = 0; r < 4; r++) {
                    int ch = (ob - 4) * 16 + quad * 4 + r;
                    Vt[((size_t)b * CIN + ch) * NPIX + n] = f2bf(acc[r] + ball[64 + ch]);
                }
            }
        }
    }
}

// ---------------------------------------------------------------------------
// Kernel 4: flash attention, load-deduplicated partition.
// 8 waves: w = kh*4 + cs. Wave (kh,cs): keys {64j + 32kh .. +32}, all 64
// q-rows, ch slice [cs*64, +64). End: kh=1 partials -> LDS, kh=0 combines,
// normalizes, stores.
#define ATTN_STEP(KC0, KC1, VC, KN0, KN1, VN, NKV)                              \
    {                                                                           \
        KN0 = *(const s8v*)(kbase + (NKV) * DQK);                               \
        KN1 = *(const s8v*)(kbase + ((NKV) + 16) * DQK);                        \
        _Pragma("unroll")                                                       \
        for (int ct = 0; ct < 4; ct++)                                          \
            VN[ct] = *(const s8v*)(vbase + ct * 16 * NPIX + (NKV));             \
        s8v pu[4];                                                              \
        _Pragma("unroll")                                                       \
        for (int rt = 0; rt < 4; rt++) {                                        \
            f4v s0 = {0.f, 0.f, 0.f, 0.f}, s1 = {0.f, 0.f, 0.f, 0.f};           \
            s0 = __builtin_amdgcn_mfma_f32_16x16x32_bf16(KC0, qf[rt], s0, 0, 0, 0); \
            s1 = __builtin_amdgcn_mfma_f32_16x16x32_bf16(KC1, qf[rt], s1, 0, 0, 0); \
            float p00 = EXP2(s0[0]), p01 = EXP2(s0[1]);                         \
            float p02 = EXP2(s0[2]), p03 = EXP2(s0[3]);                         \
            float p10 = EXP2(s1[0]), p11 = EXP2(s1[1]);                         \
            float p12 = EXP2(s1[2]), p13 = EXP2(s1[3]);                         \
            lsum[rt] += ((p00 + p01) + (p02 + p03)) + ((p10 + p11) + (p12 + p13)); \
            union { uint4 u; s8v v; } pp;                                       \
            pp.u.x = __builtin_amdgcn_perm(fbits(p01), fbits(p00), 0x07060302); \
            pp.u.y = __builtin_amdgcn_perm(fbits(p03), fbits(p02), 0x07060302); \
            pp.u.z = __builtin_amdgcn_perm(fbits(p11), fbits(p10), 0x07060302); \
            pp.u.w = __builtin_amdgcn_perm(fbits(p13), fbits(p12), 0x07060302); \
            pu[rt] = pp.v;                                                      \
        }                                                                       \
        _Pragma("unroll")                                                       \
        for (int ct = 0; ct < 4; ct++)                                          \
            _Pragma("unroll")                                                   \
            for (int rt = 0; rt < 4; rt++)                                      \
                O[rt][ct] = __builtin_amdgcn_mfma_f32_16x16x32_bf16(VC[ct], pu[rt], O[rt][ct], 0, 0, 0); \
    }

__global__ __launch_bounds__(512, 2)
void attn_kernel(const unsigned short* __restrict__ Q,
                 const unsigned short* __restrict__ Kp,
                 const unsigned short* __restrict__ Vt,
                 const float* __restrict__ gamma,
                 float* __restrict__ out) {
    __shared__ float ldsO[4][64][68];   // [cs][lane][16 f4v, padded to 17]
    __shared__ float ldsL[4][16];       // kh=1 row-sums per (rt, l16)

    int idx = blockIdx.x;
    int b      = (idx & 7) >> 1;                    // batch -> XCD pair
    int rowblk = ((idx >> 3) << 1) | (idx & 1);

    int lane = threadIdx.x & 63;
    int w    = threadIdx.x >> 6;
    int l16 = lane & 15, quad = lane >> 4;
    int kh = w >> 2;     // key-half 0..1
    int cs = w & 3;      // 64-ch slice 0..3

    const unsigned short* Kb = Kp + (size_t)b * NPIX * DQK;
    const unsigned short* Vb = Vt + (size_t)b * CIN * NPIX;

    // Q B-frags for all 4 row-tiles (log2(e) pre-folded at projection)
    int rowbase = rowblk * 64;
    s8v qf[4];
    #pragma unroll
    for (int rt = 0; rt < 4; rt++)
        qf[rt] = *(const s8v*)(Q + (size_t)(b * NPIX + rowbase + rt * 16 + l16) * DQK + quad * 8);

    const unsigned short* kbase = Kb + (32 * kh + l16) * DQK + quad * 8;
    const unsigned short* vbase = Vb + (size_t)(cs * 64 + l16) * NPIX + 32 * kh + quad * 8;

    f4v O[4][4];
    #pragma unroll
    for (int rt = 0; rt < 4; rt++)
        #pragma unroll
        for (int ct = 0; ct < 4; ct++) O[rt][ct] = (f4v){0.f, 0.f, 0.f, 0.f};
    float lsum[4] = {0.f, 0.f, 0.f, 0.f};

    s8v Vc[4], Vn[4], Kc0, Kc1, Kn0, Kn1;
    Kc0 = *(const s8v*)(kbase);
    Kc1 = *(const s8v*)(kbase + 16 * DQK);
    #pragma unroll
    for (int ct = 0; ct < 4; ct++)
        Vc[ct] = *(const s8v*)(vbase + ct * 16 * NPIX);

    for (int kv2 = 0; kv2 < NPIX; kv2 += 128) {
        ATTN_STEP(Kc0, Kc1, Vc, Kn0, Kn1, Vn, kv2 + 64);
        ATTN_STEP(Kn0, Kn1, Vn, Kc0, Kc1, Vc, (kv2 + 128) & (NPIX - 1));
    }

    // full row-sums for this key-half (reduce over quads; all lanes get value)
    #pragma unroll
    for (int rt = 0; rt < 4; rt++) {
        lsum[rt] += __shfl_xor(lsum[rt], 16);
        lsum[rt] += __shfl_xor(lsum[rt], 32);
    }

    if (kh == 1) {
        #pragma unroll
        for (int rt = 0; rt < 4; rt++)
            #pragma unroll
            for (int ct = 0; ct < 4; ct++)
                *(f4v*)&ldsO[cs][lane][(rt * 4 + ct) * 4] = O[rt][ct];
        if (cs == 0 && quad == 0) {
            #pragma unroll
            for (int rt = 0; rt < 4; rt++) ldsL[rt][l16] = lsum[rt];
        }
    }
    __syncthreads();

    if (kh == 0) {
        float g = gamma[0];
        float rinv[4];
        #pragma unroll
        for (int rt = 0; rt < 4; rt++)
            rinv[rt] = g / (lsum[rt] + ldsL[rt][l16]);
        #pragma unroll
        for (int rt = 0; rt < 4; rt++) {
            #pragma unroll
            for (int ct = 0; ct < 4; ct++) {
                f4v o2 = *(const f4v*)&ldsO[cs][lane][(rt * 4 + ct) * 4];
                #pragma unroll
                for (int r = 0; r < 4; r++) {
                    int ch = cs * 64 + ct * 16 + quad * 4 + r;
                    out[((size_t)b * CIN + ch) * NPIX + rowbase + rt * 16 + l16] =
                        (O[rt][ct][r] + o2[r]) * rinv[rt];
                }
            }
        }
    }
}

// ---------------------------------------------------------------------------
extern "C" void kernel_launch(void* const* d_in, const int* in_sizes, int n_in,
                              void* d_out, int out_size, void* d_ws, size_t ws_size,
                              hipStream_t stream) {
    const float* x     = (const float*)d_in[0];
    const float* Wq    = (const float*)d_in[1];
    const float* bq    = (const float*)d_in[2];
    const float* Wk    = (const float*)d_in[3];
    const float* bk    = (const float*)d_in[4];
    const float* Wv    = (const float*)d_in[5];
    const float* bv    = (const float*)d_in[6];
    const float* gamma = (const float*)d_in[7];
    float* out = (float*)d_out;

    char* p = (char*)d_ws;
    unsigned short* xT   = (unsigned short*)p; p += (size_t)4 * NPIX * CIN * 2;   // 8 MB
    unsigned short* Qb   = (unsigned short*)p; p += (size_t)4 * NPIX * DQK * 2;   // 1 MB
    unsigned short* Kb   = (unsigned short*)p; p += (size_t)4 * NPIX * DQK * 2;   // 1 MB
    unsigned short* Vt   = (unsigned short*)p; p += (size_t)4 * CIN * NPIX * 2;   // 8 MB
    unsigned short* Wall = (unsigned short*)p; p += (size_t)320 * 256 * 2;
    float*          ball = (float*)p;          p += (size_t)320 * 4;

    wcast_kernel<<<320, 256, 0, stream>>>(Wq, bq, Wk, bk, Wv, bv, Wall, ball);
    tcast_kernel<<<1024, 256, 0, stream>>>(x, xT);
    proj_kernel<<<256, 256, 0, stream>>>(xT, Wall, ball, Qb, Kb, Vt);
    attn_kernel<<<256, 512, 0, stream>>>(Qb, Kb, Vt, gamma, out);
}